// Round 2
// baseline (646.043 us; speedup 1.0000x reference)
//
#include <hip/hip_runtime.h>

#define NN 50000
#define NE 800000
#define NCHUNK 196  // ceil(NN/256)

// ================= CSR build =================

__global__ void deg_count_kernel(const int* __restrict__ dst, int* __restrict__ counts) {
    int e = blockIdx.x * 256 + threadIdx.x;
    if (e < NE) atomicAdd(&counts[dst[e]], 1);
}

__global__ void chunk_sum_kernel(const int* __restrict__ counts, int* __restrict__ partials) {
    int i = blockIdx.x * 256 + threadIdx.x;
    int v = (i < NN) ? counts[i] : 0;
    for (int o = 32; o; o >>= 1) v += __shfl_down(v, o);
    __shared__ int red[4];
    if ((threadIdx.x & 63) == 0) red[threadIdx.x >> 6] = v;
    __syncthreads();
    if (threadIdx.x == 0) partials[blockIdx.x] = red[0] + red[1] + red[2] + red[3];
}

__global__ void scan_partials_kernel(const int* __restrict__ partials, int* __restrict__ chunk_off) {
    __shared__ int s[256];
    int t = threadIdx.x;
    int v = (t < NCHUNK) ? partials[t] : 0;
    s[t] = v;
    __syncthreads();
    for (int o = 1; o < 256; o <<= 1) {
        int u = (t >= o) ? s[t - o] : 0;
        __syncthreads();
        s[t] += u;
        __syncthreads();
    }
    chunk_off[t] = s[t] - v;  // exclusive
}

__global__ void scan_chunks_kernel(const int* __restrict__ counts, const int* __restrict__ chunk_off,
                                   int* __restrict__ row_ptr, int* __restrict__ cursor,
                                   float* __restrict__ dinv) {
    __shared__ int s[256];
    int b = blockIdx.x, t = threadIdx.x;
    int i = b * 256 + t;
    int c = (i < NN) ? counts[i] : 0;
    s[t] = c;
    __syncthreads();
    for (int o = 1; o < 256; o <<= 1) {
        int u = (t >= o) ? s[t - o] : 0;
        __syncthreads();
        s[t] += u;
        __syncthreads();
    }
    if (i < NN) {
        int start = chunk_off[b] + s[t] - c;  // exclusive prefix
        row_ptr[i] = start;
        cursor[i]  = start;
        dinv[i] = rsqrtf((float)(c + 1));  // +1 self loop
    }
}

__global__ void fill_csr_kernel(const int* __restrict__ src, const int* __restrict__ dst,
                                const float* __restrict__ dinv, int* __restrict__ cursor,
                                int* __restrict__ srcs, float* __restrict__ nrms) {
    int e = blockIdx.x * 256 + threadIdx.x;
    if (e >= NE) return;
    int s_ = src[e], d = dst[e];
    int p = atomicAdd(&cursor[d], 1);
    srcs[p] = s_;
    nrms[p] = dinv[s_] * dinv[d];
}

// ================= SGEMM: C[M,256] = act(A[M,256]) @ W[256,256] =================
// act = relu(a + bias[k]) when RELU_BIAS (fuses layer-1 bias+relu into GEMM2's A-load)

template <bool RELU_BIAS>
__global__ __launch_bounds__(256) void sgemm_kernel(const float* __restrict__ A,
                                                    const float* __restrict__ W,
                                                    const float* __restrict__ bias,
                                                    float* __restrict__ C, int M) {
    __shared__ float As[16][64];
    __shared__ float Ws[16][64];
    const int tid = threadIdx.x;
    const int row0 = blockIdx.x * 64;
    const int col0 = blockIdx.y * 64;
    const int tm = tid >> 4;          // 0..15
    const int tn = tid & 15;          // 0..15
    const int am = tid >> 2;          // 0..63   A-tile row
    const int ak = (tid & 3) * 4;     // 0,4,8,12 A-tile k offset
    const int wk = tid >> 4;          // 0..15   W-tile k
    const int wn = (tid & 15) * 4;    // 0..60   W-tile col offset

    float acc[4][4] = {};

    for (int k0 = 0; k0 < 256; k0 += 16) {
        int arow = row0 + am;
        float4 av;
        if (arow < M) av = *(const float4*)&A[(size_t)arow * 256 + k0 + ak];
        else          av = make_float4(0.f, 0.f, 0.f, 0.f);
        if (RELU_BIAS) {
            av.x = fmaxf(av.x + bias[k0 + ak + 0], 0.f);
            av.y = fmaxf(av.y + bias[k0 + ak + 1], 0.f);
            av.z = fmaxf(av.z + bias[k0 + ak + 2], 0.f);
            av.w = fmaxf(av.w + bias[k0 + ak + 3], 0.f);
        }
        As[ak + 0][am] = av.x;
        As[ak + 1][am] = av.y;
        As[ak + 2][am] = av.z;
        As[ak + 3][am] = av.w;

        *(float4*)&Ws[wk][wn] = *(const float4*)&W[(size_t)(k0 + wk) * 256 + col0 + wn];
        __syncthreads();

#pragma unroll
        for (int k = 0; k < 16; ++k) {
            float4 a = *(const float4*)&As[k][tm * 4];
            float4 b = *(const float4*)&Ws[k][tn * 4];
            acc[0][0] += a.x * b.x; acc[0][1] += a.x * b.y; acc[0][2] += a.x * b.z; acc[0][3] += a.x * b.w;
            acc[1][0] += a.y * b.x; acc[1][1] += a.y * b.y; acc[1][2] += a.y * b.z; acc[1][3] += a.y * b.w;
            acc[2][0] += a.z * b.x; acc[2][1] += a.z * b.y; acc[2][2] += a.z * b.z; acc[2][3] += a.z * b.w;
            acc[3][0] += a.w * b.x; acc[3][1] += a.w * b.y; acc[3][2] += a.w * b.z; acc[3][3] += a.w * b.w;
        }
        __syncthreads();
    }

#pragma unroll
    for (int i = 0; i < 4; ++i) {
        int r = row0 + tm * 4 + i;
        if (r < M) {
            float4 v = make_float4(acc[i][0], acc[i][1], acc[i][2], acc[i][3]);
            *(float4*)&C[(size_t)r * 256 + col0 + tn * 4] = v;
        }
    }
}

// ================= CSR aggregation: one wave per destination node =================
// agg[d,:] = xw[d,:]*dinv[d]^2 + sum_{e: dst=d} xw[src_e,:]*nrm_e      (no atomics)

__global__ __launch_bounds__(256) void aggregate_kernel(const float* __restrict__ xw,
                                                        const int* __restrict__ row_ptr,
                                                        const int* __restrict__ counts,
                                                        const int* __restrict__ srcs,
                                                        const float* __restrict__ nrms,
                                                        const float* __restrict__ dinv,
                                                        float* __restrict__ agg) {
    int d = blockIdx.x * 4 + (threadIdx.x >> 6);  // node id (wave per node)
    if (d >= NN) return;
    int lane = threadIdx.x & 63;

    float di = dinv[d];
    float s2 = di * di;
    float4 acc = *(const float4*)&xw[(size_t)d * 256 + lane * 4];
    acc.x *= s2; acc.y *= s2; acc.z *= s2; acc.w *= s2;

    int start = row_ptr[d];
    int end = start + counts[d];
    for (int j = start; j < end; ++j) {
        int s_ = srcs[j];       // wave-uniform broadcast
        float w = nrms[j];
        const float4 v = *(const float4*)&xw[(size_t)s_ * 256 + lane * 4];
        acc.x = fmaf(v.x, w, acc.x);
        acc.y = fmaf(v.y, w, acc.y);
        acc.z = fmaf(v.z, w, acc.z);
        acc.w = fmaf(v.w, w, acc.w);
    }
    *(float4*)&agg[(size_t)d * 256 + lane * 4] = acc;
}

// ================= fused epilogue =================
// out[i] = (agg2[i,:]+b2) . Wf[0:256] + relu(tf[i,:]@Wt+bt) . Wf[256:512] + bf

__global__ __launch_bounds__(256) void final_kernel(const float* __restrict__ agg2,
                                                    const float* __restrict__ b2,
                                                    const float* __restrict__ tf,
                                                    const float* __restrict__ Wt,
                                                    const float* __restrict__ bt,
                                                    const float* __restrict__ Wf,
                                                    const float* __restrict__ bf,
                                                    float* __restrict__ out) {
    int i = blockIdx.x;
    int c = threadIdx.x;  // 256
    float xg = agg2[(size_t)i * 256 + c] + b2[c];
    float acc = xg * Wf[c];
    float t0 = tf[i * 2 + 0], t1 = tf[i * 2 + 1];
    float xt = fmaxf(fmaf(t0, Wt[c], fmaf(t1, Wt[256 + c], bt[c])), 0.f);
    acc = fmaf(xt, Wf[256 + c], acc);

    acc += __shfl_down(acc, 32);
    acc += __shfl_down(acc, 16);
    acc += __shfl_down(acc, 8);
    acc += __shfl_down(acc, 4);
    acc += __shfl_down(acc, 2);
    acc += __shfl_down(acc, 1);
    __shared__ float red[4];
    if ((c & 63) == 0) red[c >> 6] = acc;
    __syncthreads();
    if (c == 0) out[i] = red[0] + red[1] + red[2] + red[3] + bf[0];
}

// ================= launch =================

extern "C" void kernel_launch(void* const* d_in, const int* in_sizes, int n_in,
                              void* d_out, int out_size, void* d_ws, size_t ws_size,
                              hipStream_t stream) {
    const float* x  = (const float*)d_in[0];
    const int*   ei = (const int*)d_in[1];      // [2, NE] int32
    const float* tf = (const float*)d_in[2];
    const float* W1 = (const float*)d_in[3];
    const float* b1 = (const float*)d_in[4];
    const float* W2 = (const float*)d_in[5];
    const float* b2 = (const float*)d_in[6];
    const float* Wt = (const float*)d_in[7];
    const float* bt = (const float*)d_in[8];
    const float* Wf = (const float*)d_in[9];
    const float* bf = (const float*)d_in[10];
    const int* srcp = ei;
    const int* dstp = ei + NE;

    // workspace layout (all offsets 256B-aligned)
    char* ws = (char*)d_ws;
    float* A       = (float*)(ws);                       // 51,200,000  xw / xw2
    float* B       = (float*)(ws + 51200000);            // 51,200,000  agg1 / agg2
    char*  p       = ws + 102400000;
    int*   counts  = (int*)(p);            p += 204800;  // NN ints
    float* dinv    = (float*)(p);          p += 204800;  // NN floats
    int*   row_ptr = (int*)(p);            p += 204800;  // NN ints
    int*   cursor  = (int*)(p);            p += 204800;  // NN ints
    int*   partials= (int*)(p);            p += 4096;    // NCHUNK ints
    int*   chunkoff= (int*)(p);            p += 4096;    // 256 ints
    int*   srcs    = (int*)(p);            p += 3200000; // NE ints
    float* nrms    = (float*)(p);          p += 3200000; // NE floats
    // total ~109.8 MB

    // ---- CSR build (d_ws is poisoned 0xAA every call -> must zero counts) ----
    hipMemsetAsync(counts, 0, NN * sizeof(int), stream);
    deg_count_kernel<<<(NE + 255) / 256, 256, 0, stream>>>(dstp, counts);
    chunk_sum_kernel<<<NCHUNK, 256, 0, stream>>>(counts, partials);
    scan_partials_kernel<<<1, 256, 0, stream>>>(partials, chunkoff);
    scan_chunks_kernel<<<NCHUNK, 256, 0, stream>>>(counts, chunkoff, row_ptr, cursor, dinv);
    fill_csr_kernel<<<(NE + 255) / 256, 256, 0, stream>>>(srcp, dstp, dinv, cursor, srcs, nrms);

    dim3 gemm_grid((NN + 63) / 64, 4);
    dim3 agg_grid((NN + 3) / 4);

    // layer 1
    sgemm_kernel<false><<<gemm_grid, 256, 0, stream>>>(x, W1, nullptr, A, NN);
    aggregate_kernel<<<agg_grid, 256, 0, stream>>>(A, row_ptr, counts, srcs, nrms, dinv, B);

    // layer 2 (bias1+relu fused into GEMM A-load)
    sgemm_kernel<true><<<gemm_grid, 256, 0, stream>>>(B, W2, b1, A, NN);
    aggregate_kernel<<<agg_grid, 256, 0, stream>>>(A, row_ptr, counts, srcs, nrms, dinv, B);

    // epilogue
    final_kernel<<<NN, 256, 0, stream>>>(B, b2, tf, Wt, bt, Wf, bf, (float*)d_out);
}

// Round 10
// 539.635 us; speedup vs baseline: 1.1972x; 1.1972x over previous
//
#include <hip/hip_runtime.h>

#define NN 50000
#define NE 800000
#define NCHUNK 196  // ceil(NN/256)

typedef __attribute__((ext_vector_type(4))) float f32x4;
typedef __attribute__((ext_vector_type(8))) short bf16x8;

// bf16 round-to-nearest-even split helpers
__device__ __forceinline__ short f2bf(float x) {
    unsigned u = __float_as_uint(x);
    unsigned r = (u + 0x7fffu + ((u >> 16) & 1u)) >> 16;
    return (short)r;
}
__device__ __forceinline__ float bf2f(short s) {
    return __uint_as_float(((unsigned)(unsigned short)s) << 16);
}

// ================= CSR build =================

__global__ void deg_count_kernel(const int* __restrict__ dst, int* __restrict__ counts) {
    int e = blockIdx.x * 256 + threadIdx.x;
    if (e < NE) atomicAdd(&counts[dst[e]], 1);
}

__global__ void chunk_sum_kernel(const int* __restrict__ counts, int* __restrict__ partials) {
    int i = blockIdx.x * 256 + threadIdx.x;
    int v = (i < NN) ? counts[i] : 0;
    for (int o = 32; o; o >>= 1) v += __shfl_down(v, o);
    __shared__ int red[4];
    if ((threadIdx.x & 63) == 0) red[threadIdx.x >> 6] = v;
    __syncthreads();
    if (threadIdx.x == 0) partials[blockIdx.x] = red[0] + red[1] + red[2] + red[3];
}

__global__ void scan_partials_kernel(const int* __restrict__ partials, int* __restrict__ chunk_off) {
    __shared__ int s[256];
    int t = threadIdx.x;
    int v = (t < NCHUNK) ? partials[t] : 0;
    s[t] = v;
    __syncthreads();
    for (int o = 1; o < 256; o <<= 1) {
        int u = (t >= o) ? s[t - o] : 0;
        __syncthreads();
        s[t] += u;
        __syncthreads();
    }
    chunk_off[t] = s[t] - v;  // exclusive
}

__global__ void scan_chunks_kernel(const int* __restrict__ counts, const int* __restrict__ chunk_off,
                                   int* __restrict__ row_ptr, int* __restrict__ cursor,
                                   float* __restrict__ dinv) {
    __shared__ int s[256];
    int b = blockIdx.x, t = threadIdx.x;
    int i = b * 256 + t;
    int c = (i < NN) ? counts[i] : 0;
    s[t] = c;
    __syncthreads();
    for (int o = 1; o < 256; o <<= 1) {
        int u = (t >= o) ? s[t - o] : 0;
        __syncthreads();
        s[t] += u;
        __syncthreads();
    }
    if (i < NN) {
        int start = chunk_off[b] + s[t] - c;  // exclusive prefix
        row_ptr[i] = start;
        cursor[i]  = start;
        dinv[i] = rsqrtf((float)(c + 1));  // +1 self loop
    }
}

__global__ void fill_csr_kernel(const int* __restrict__ src, const int* __restrict__ dst,
                                const float* __restrict__ dinv, int* __restrict__ cursor,
                                int* __restrict__ srcs, float* __restrict__ nrms) {
    int e = blockIdx.x * 256 + threadIdx.x;
    if (e >= NE) return;
    int s_ = src[e], d = dst[e];
    int p = atomicAdd(&cursor[d], 1);
    srcs[p] = s_;
    nrms[p] = dinv[s_] * dinv[d];
}

// ================= split-bf16 MFMA GEMM: C[M,256] = act(A[M,256]) @ W[256,256] =================
// A fp32 -> hi/lo bf16 split during LDS staging; W fp32 read directly (L2-resident,
// 256KB) and split+transposed in-kernel -- no extra d_ws weight buffers (keeps the
// workspace footprint identical to the round-2 kernel that passed on-device).
// hi*hi + hi*lo + lo*hi (lo*lo dropped) -> ~fp32 accuracy.
// act = relu(a + bias[k]) when RELU_BIAS (fuses layer-1 bias+relu into GEMM2's A-load).

#define BM 64
#define BK 32
#define PK 40  // padded k-stride in LDS (80B rows -> 2-way banks, free)

template <bool RELU_BIAS>
__global__ __launch_bounds__(256) void mgemm_kernel(const float* __restrict__ A,
                                                    const float* __restrict__ W,
                                                    const float* __restrict__ bias,
                                                    float* __restrict__ C, int M) {
    __shared__ __align__(16) short Ah[BM * PK], Al[BM * PK];
    __shared__ __align__(16) short Bh[256 * PK], Bl[256 * PK];
    const int tid  = threadIdx.x;
    const int lane = tid & 63;
    const int wave = tid >> 6;
    const int row0 = blockIdx.x * BM;
    const int wcol = wave * 64;   // this wave's 64-col slice of N=256

    const int l15 = lane & 15;
    const int kb  = (lane >> 4) * 8;   // k-block of this lane within frag

    const int arow  = tid >> 2;        // 0..63   A staging row
    const int akoff = (tid & 3) * 8;   // 0,8,16,24

    f32x4 acc[4][4] = {};  // [mf][nf] 16x16 frags -> 64x64 per wave

    for (int k0 = 0; k0 < 256; k0 += BK) {
        // ---- load + convert A slice ----
        float xv[8];
        int grow = row0 + arow;
        if (grow < M) {
            float4 a0 = *(const float4*)&A[(size_t)grow * 256 + k0 + akoff];
            float4 a1 = *(const float4*)&A[(size_t)grow * 256 + k0 + akoff + 4];
            xv[0] = a0.x; xv[1] = a0.y; xv[2] = a0.z; xv[3] = a0.w;
            xv[4] = a1.x; xv[5] = a1.y; xv[6] = a1.z; xv[7] = a1.w;
        } else {
#pragma unroll
            for (int i = 0; i < 8; ++i) xv[i] = 0.f;
        }
        if (RELU_BIAS) {
#pragma unroll
            for (int i = 0; i < 8; ++i) xv[i] = fmaxf(xv[i] + bias[k0 + akoff + i], 0.f);
        }
        bf16x8 hv, lv;
#pragma unroll
        for (int i = 0; i < 8; ++i) {
            short h = f2bf(xv[i]);
            hv[i] = h;
            lv[i] = f2bf(xv[i] - bf2f(h));
        }

        // ---- load W slice: thread t reads W[k0+c][t] (coalesced across t) ----
        float wv[BK];
#pragma unroll
        for (int c = 0; c < BK; ++c) wv[c] = W[(size_t)(k0 + c) * 256 + tid];

        __syncthreads();  // previous iter's frag reads done before overwrite
        *(bf16x8*)&Ah[arow * PK + akoff] = hv;
        *(bf16x8*)&Al[arow * PK + akoff] = lv;

        // B-tile stored transposed: row n=tid, col k (contiguous k for frag reads)
#pragma unroll
        for (int c = 0; c < BK; ++c) {
            short h = f2bf(wv[c]);
            Bh[tid * PK + c] = h;
            Bl[tid * PK + c] = f2bf(wv[c] - bf2f(h));
        }
        __syncthreads();

        // ---- MFMA: 16 frag-pairs x 3 products ----
        bf16x8 bh[4], bl[4];
#pragma unroll
        for (int nf = 0; nf < 4; ++nf) {
            int col = wcol + nf * 16 + l15;
            bh[nf] = *(const bf16x8*)&Bh[col * PK + kb];
            bl[nf] = *(const bf16x8*)&Bl[col * PK + kb];
        }
#pragma unroll
        for (int mf = 0; mf < 4; ++mf) {
            int r = mf * 16 + l15;
            bf16x8 ah = *(const bf16x8*)&Ah[r * PK + kb];
            bf16x8 al = *(const bf16x8*)&Al[r * PK + kb];
#pragma unroll
            for (int nf = 0; nf < 4; ++nf) {
                acc[mf][nf] = __builtin_amdgcn_mfma_f32_16x16x32_bf16(ah, bh[nf], acc[mf][nf], 0, 0, 0);
                acc[mf][nf] = __builtin_amdgcn_mfma_f32_16x16x32_bf16(ah, bl[nf], acc[mf][nf], 0, 0, 0);
                acc[mf][nf] = __builtin_amdgcn_mfma_f32_16x16x32_bf16(al, bh[nf], acc[mf][nf], 0, 0, 0);
            }
        }
    }

    // ---- store: D row = 4*(lane>>4)+r, col = lane&15 ----
    const int orow = 4 * (lane >> 4);
#pragma unroll
    for (int mf = 0; mf < 4; ++mf) {
#pragma unroll
        for (int r = 0; r < 4; ++r) {
            int grow = row0 + mf * 16 + orow + r;
            if (grow < M) {
#pragma unroll
                for (int nf = 0; nf < 4; ++nf) {
                    C[(size_t)grow * 256 + wcol + nf * 16 + l15] = acc[mf][nf][r];
                }
            }
        }
    }
}

// ================= CSR aggregation: one wave per destination node =================
// agg[d,:] = xw[d,:]*dinv[d]^2 + sum_{e: dst=d} xw[src_e,:]*nrm_e
// unroll-4: 4 independent gathers in flight (attacks the latency bound)

__global__ __launch_bounds__(256) void aggregate_kernel(const float* __restrict__ xw,
                                                        const int* __restrict__ row_ptr,
                                                        const int* __restrict__ counts,
                                                        const int* __restrict__ srcs,
                                                        const float* __restrict__ nrms,
                                                        const float* __restrict__ dinv,
                                                        float* __restrict__ agg) {
    int d = blockIdx.x * 4 + (threadIdx.x >> 6);
    if (d >= NN) return;
    int lane = threadIdx.x & 63;

    float di = dinv[d];
    float s2 = di * di;
    float4 acc = *(const float4*)&xw[(size_t)d * 256 + lane * 4];
    acc.x *= s2; acc.y *= s2; acc.z *= s2; acc.w *= s2;

    int j = row_ptr[d];
    int cnt = counts[d];

    for (; cnt >= 4; cnt -= 4, j += 4) {
        int s0 = srcs[j + 0], s1 = srcs[j + 1], s2i = srcs[j + 2], s3 = srcs[j + 3];
        float w0 = nrms[j + 0], w1 = nrms[j + 1], w2 = nrms[j + 2], w3 = nrms[j + 3];
        const float4 v0 = *(const float4*)&xw[(size_t)s0 * 256 + lane * 4];
        const float4 v1 = *(const float4*)&xw[(size_t)s1 * 256 + lane * 4];
        const float4 v2 = *(const float4*)&xw[(size_t)s2i * 256 + lane * 4];
        const float4 v3 = *(const float4*)&xw[(size_t)s3 * 256 + lane * 4];
        acc.x = fmaf(v0.x, w0, acc.x); acc.y = fmaf(v0.y, w0, acc.y);
        acc.z = fmaf(v0.z, w0, acc.z); acc.w = fmaf(v0.w, w0, acc.w);
        acc.x = fmaf(v1.x, w1, acc.x); acc.y = fmaf(v1.y, w1, acc.y);
        acc.z = fmaf(v1.z, w1, acc.z); acc.w = fmaf(v1.w, w1, acc.w);
        acc.x = fmaf(v2.x, w2, acc.x); acc.y = fmaf(v2.y, w2, acc.y);
        acc.z = fmaf(v2.z, w2, acc.z); acc.w = fmaf(v2.w, w2, acc.w);
        acc.x = fmaf(v3.x, w3, acc.x); acc.y = fmaf(v3.y, w3, acc.y);
        acc.z = fmaf(v3.z, w3, acc.z); acc.w = fmaf(v3.w, w3, acc.w);
    }
    for (; cnt > 0; --cnt, ++j) {
        int s_ = srcs[j];
        float w = nrms[j];
        const float4 v = *(const float4*)&xw[(size_t)s_ * 256 + lane * 4];
        acc.x = fmaf(v.x, w, acc.x);
        acc.y = fmaf(v.y, w, acc.y);
        acc.z = fmaf(v.z, w, acc.z);
        acc.w = fmaf(v.w, w, acc.w);
    }
    *(float4*)&agg[(size_t)d * 256 + lane * 4] = acc;
}

// ================= fused epilogue: wave per node =================
// out[i] = (agg2[i,:]+b2) . Wf[0:256] + relu(tf[i,:]@Wt+bt) . Wf[256:512] + bf

__global__ __launch_bounds__(256) void final_kernel(const float* __restrict__ agg2,
                                                    const float* __restrict__ b2,
                                                    const float* __restrict__ tf,
                                                    const float* __restrict__ Wt,
                                                    const float* __restrict__ bt,
                                                    const float* __restrict__ Wf,
                                                    const float* __restrict__ bf,
                                                    float* __restrict__ out) {
    int d = blockIdx.x * 4 + (threadIdx.x >> 6);
    if (d >= NN) return;
    int lane = threadIdx.x & 63;
    int c0 = lane * 4;

    float4 g   = *(const float4*)&agg2[(size_t)d * 256 + c0];
    float4 b2v = *(const float4*)&b2[c0];
    float4 wf0 = *(const float4*)&Wf[c0];
    float4 wf1 = *(const float4*)&Wf[256 + c0];
    float4 wt0 = *(const float4*)&Wt[c0];        // Wt row 0
    float4 wt1 = *(const float4*)&Wt[256 + c0];  // Wt row 1
    float4 btv = *(const float4*)&bt[c0];
    float t0 = tf[d * 2 + 0], t1 = tf[d * 2 + 1];

    float acc = (g.x + b2v.x) * wf0.x + (g.y + b2v.y) * wf0.y +
                (g.z + b2v.z) * wf0.z + (g.w + b2v.w) * wf0.w;
    float xt;
    xt = fmaxf(fmaf(t0, wt0.x, fmaf(t1, wt1.x, btv.x)), 0.f); acc = fmaf(xt, wf1.x, acc);
    xt = fmaxf(fmaf(t0, wt0.y, fmaf(t1, wt1.y, btv.y)), 0.f); acc = fmaf(xt, wf1.y, acc);
    xt = fmaxf(fmaf(t0, wt0.z, fmaf(t1, wt1.z, btv.z)), 0.f); acc = fmaf(xt, wf1.z, acc);
    xt = fmaxf(fmaf(t0, wt0.w, fmaf(t1, wt1.w, btv.w)), 0.f); acc = fmaf(xt, wf1.w, acc);

    acc += __shfl_down(acc, 32);
    acc += __shfl_down(acc, 16);
    acc += __shfl_down(acc, 8);
    acc += __shfl_down(acc, 4);
    acc += __shfl_down(acc, 2);
    acc += __shfl_down(acc, 1);
    if (lane == 0) out[d] = acc + bf[0];
}

// ================= launch =================

extern "C" void kernel_launch(void* const* d_in, const int* in_sizes, int n_in,
                              void* d_out, int out_size, void* d_ws, size_t ws_size,
                              hipStream_t stream) {
    const float* x  = (const float*)d_in[0];
    const int*   ei = (const int*)d_in[1];      // [2, NE] int32
    const float* tf = (const float*)d_in[2];
    const float* W1 = (const float*)d_in[3];
    const float* b1 = (const float*)d_in[4];
    const float* W2 = (const float*)d_in[5];
    const float* b2 = (const float*)d_in[6];
    const float* Wt = (const float*)d_in[7];
    const float* bt = (const float*)d_in[8];
    const float* Wf = (const float*)d_in[9];
    const float* bf = (const float*)d_in[10];
    const int* srcp = ei;
    const int* dstp = ei + NE;

    // workspace layout -- identical footprint to the round-2 kernel that passed
    char* ws = (char*)d_ws;
    float* A       = (float*)(ws);                       // 51,200,000  xw / xw2
    float* B       = (float*)(ws + 51200000);            // 51,200,000  agg1 / agg2
    char*  p       = ws + 102400000;
    int*   counts  = (int*)(p);            p += 204800;
    float* dinv    = (float*)(p);          p += 204800;
    int*   row_ptr = (int*)(p);            p += 204800;
    int*   cursor  = (int*)(p);            p += 204800;
    int*   partials= (int*)(p);            p += 4096;
    int*   chunkoff= (int*)(p);            p += 4096;
    int*   srcs    = (int*)(p);            p += 3200000;
    float* nrms    = (float*)(p);          p += 3200000;
    // total ~109.8 MB

    // ---- CSR build (d_ws poisoned 0xAA every call -> zero counts first) ----
    hipMemsetAsync(counts, 0, NN * sizeof(int), stream);
    deg_count_kernel<<<(NE + 255) / 256, 256, 0, stream>>>(dstp, counts);
    chunk_sum_kernel<<<NCHUNK, 256, 0, stream>>>(counts, partials);
    scan_partials_kernel<<<1, 256, 0, stream>>>(partials, chunkoff);
    scan_chunks_kernel<<<NCHUNK, 256, 0, stream>>>(counts, chunkoff, row_ptr, cursor, dinv);
    fill_csr_kernel<<<(NE + 255) / 256, 256, 0, stream>>>(srcp, dstp, dinv, cursor, srcs, nrms);

    int gemm_grid = (NN + BM - 1) / BM;  // 782
    dim3 agg_grid((NN + 3) / 4);

    // layer 1
    mgemm_kernel<false><<<gemm_grid, 256, 0, stream>>>(x, W1, nullptr, A, NN);
    aggregate_kernel<<<agg_grid, 256, 0, stream>>>(A, row_ptr, counts, srcs, nrms, dinv, B);

    // layer 2 (bias1+relu fused into GEMM A-load)
    mgemm_kernel<true><<<gemm_grid, 256, 0, stream>>>(B, W2, b1, A, NN);
    aggregate_kernel<<<agg_grid, 256, 0, stream>>>(A, row_ptr, counts, srcs, nrms, dinv, B);

    // epilogue
    final_kernel<<<agg_grid, 256, 0, stream>>>(B, b2, tf, Wt, bt, Wf, bf, (float*)d_out);
}

// Round 12
// 433.625 us; speedup vs baseline: 1.4899x; 1.2445x over previous
//
#include <hip/hip_runtime.h>

#define NN 50000
#define NE 800000
#define NCHUNK 196  // ceil(NN/256)

typedef __attribute__((ext_vector_type(4))) float f32x4;
typedef __attribute__((ext_vector_type(8))) short bf16x8;
typedef __attribute__((ext_vector_type(4))) short bf16x4;

// bf16 round-to-nearest-even helpers
__device__ __forceinline__ short f2bf(float x) {
    unsigned u = __float_as_uint(x);
    unsigned r = (u + 0x7fffu + ((u >> 16) & 1u)) >> 16;
    return (short)r;
}
__device__ __forceinline__ float bf2f(short s) {
    return __uint_as_float(((unsigned)(unsigned short)s) << 16);
}

// ================= CSR build =================

__global__ void deg_count_kernel(const int* __restrict__ dst, int* __restrict__ counts) {
    int e = blockIdx.x * 256 + threadIdx.x;
    if (e < NE) atomicAdd(&counts[dst[e]], 1);
}

__global__ void chunk_sum_kernel(const int* __restrict__ counts, int* __restrict__ partials) {
    int i = blockIdx.x * 256 + threadIdx.x;
    int v = (i < NN) ? counts[i] : 0;
    for (int o = 32; o; o >>= 1) v += __shfl_down(v, o);
    __shared__ int red[4];
    if ((threadIdx.x & 63) == 0) red[threadIdx.x >> 6] = v;
    __syncthreads();
    if (threadIdx.x == 0) partials[blockIdx.x] = red[0] + red[1] + red[2] + red[3];
}

__global__ void scan_partials_kernel(const int* __restrict__ partials, int* __restrict__ chunk_off) {
    __shared__ int s[256];
    int t = threadIdx.x;
    int v = (t < NCHUNK) ? partials[t] : 0;
    s[t] = v;
    __syncthreads();
    for (int o = 1; o < 256; o <<= 1) {
        int u = (t >= o) ? s[t - o] : 0;
        __syncthreads();
        s[t] += u;
        __syncthreads();
    }
    chunk_off[t] = s[t] - v;  // exclusive
}

__global__ void scan_chunks_kernel(const int* __restrict__ counts, const int* __restrict__ chunk_off,
                                   int* __restrict__ row_ptr, int* __restrict__ cursor,
                                   float* __restrict__ dinv) {
    __shared__ int s[256];
    int b = blockIdx.x, t = threadIdx.x;
    int i = b * 256 + t;
    int c = (i < NN) ? counts[i] : 0;
    s[t] = c;
    __syncthreads();
    for (int o = 1; o < 256; o <<= 1) {
        int u = (t >= o) ? s[t - o] : 0;
        __syncthreads();
        s[t] += u;
        __syncthreads();
    }
    if (i < NN) {
        int start = chunk_off[b] + s[t] - c;  // exclusive prefix
        row_ptr[i] = start;
        cursor[i]  = start;
        dinv[i] = rsqrtf((float)(c + 1));  // +1 self loop
    }
}

__global__ void fill_csr_kernel(const int* __restrict__ src, const int* __restrict__ dst,
                                const float* __restrict__ dinv, int* __restrict__ cursor,
                                int* __restrict__ srcs, float* __restrict__ nrms) {
    int e = blockIdx.x * 256 + threadIdx.x;
    if (e >= NE) return;
    int s_ = src[e], d = dst[e];
    int p = atomicAdd(&cursor[d], 1);
    srcs[p] = s_;
    nrms[p] = dinv[s_] * dinv[d];
}

// ================= W pre-pass: transpose + split to bf16 hi/lo =================
// in:  W [K=256][N=256] row-major fp32 ; out: Wh/Wl [N][K] bf16 bits

__global__ void wconv_kernel(const float* __restrict__ W, short* __restrict__ Wh,
                             short* __restrict__ Wl) {
    int idx = blockIdx.x * 256 + threadIdx.x;  // 65536
    int k = idx >> 8, n = idx & 255;
    float x = W[idx];
    short h = f2bf(x);
    short l = f2bf(x - bf2f(h));
    Wh[n * 256 + k] = h;
    Wl[n * 256 + k] = l;
}

// ================= split-bf16 MFMA GEMM: C_bf16[M,256] = act(A[M,256]) @ W =================
// A fp32 -> hi/lo bf16 split during LDS staging; W pre-split/pre-transposed (round-2
// proven layout). C stored as bf16 ONLY: xw is consumed exclusively by the gather-
// bound aggregate, so bf16 halves its 402MB L2-miss traffic (the measured bottleneck).
// hi*hi + hi*lo + lo*hi (lo*lo dropped) -> ~fp32 mantissa for the matmul itself.
// act = relu(a + bias[k]) when RELU_BIAS (fuses layer-1 bias+relu into GEMM2's A-load).

#define BM 64
#define BK 32
#define PK 40  // padded k-stride in LDS (80B rows -> 2-way banks, free)

template <bool RELU_BIAS>
__global__ __launch_bounds__(256) void mgemm_kernel(const float* __restrict__ A,
                                                    const short* __restrict__ Wh,
                                                    const short* __restrict__ Wl,
                                                    const float* __restrict__ bias,
                                                    short* __restrict__ C, int M) {
    __shared__ __align__(16) short Ah[BM * PK], Al[BM * PK];
    __shared__ __align__(16) short Bh[256 * PK], Bl[256 * PK];
    const int tid  = threadIdx.x;
    const int lane = tid & 63;
    const int wave = tid >> 6;
    const int row0 = blockIdx.x * BM;
    const int wcol = wave * 64;   // this wave's 64-col slice of N=256

    const int l15 = lane & 15;
    const int kb  = (lane >> 4) * 8;   // k-block of this lane within frag

    const int arow  = tid >> 2;        // 0..63   A staging row
    const int akoff = (tid & 3) * 8;   // 0,8,16,24

    f32x4 acc[4][4] = {};  // [mf][nf] 16x16 frags -> 64x64 per wave

    for (int k0 = 0; k0 < 256; k0 += BK) {
        // ---- load + convert A slice ----
        float xv[8];
        int grow = row0 + arow;
        if (grow < M) {
            float4 a0 = *(const float4*)&A[(size_t)grow * 256 + k0 + akoff];
            float4 a1 = *(const float4*)&A[(size_t)grow * 256 + k0 + akoff + 4];
            xv[0] = a0.x; xv[1] = a0.y; xv[2] = a0.z; xv[3] = a0.w;
            xv[4] = a1.x; xv[5] = a1.y; xv[6] = a1.z; xv[7] = a1.w;
        } else {
#pragma unroll
            for (int i = 0; i < 8; ++i) xv[i] = 0.f;
        }
        if (RELU_BIAS) {
#pragma unroll
            for (int i = 0; i < 8; ++i) xv[i] = fmaxf(xv[i] + bias[k0 + akoff + i], 0.f);
        }
        bf16x8 hv, lv;
#pragma unroll
        for (int i = 0; i < 8; ++i) {
            short h = f2bf(xv[i]);
            hv[i] = h;
            lv[i] = f2bf(xv[i] - bf2f(h));
        }

        __syncthreads();  // previous iter's frag reads done before overwrite
        *(bf16x8*)&Ah[arow * PK + akoff] = hv;
        *(bf16x8*)&Al[arow * PK + akoff] = lv;

        // ---- stage B slice: thread t owns row n=t (vector loads, pre-split W) ----
        {
            const short* sh = &Wh[tid * 256 + k0];
            const short* sl = &Wl[tid * 256 + k0];
#pragma unroll
            for (int c = 0; c < 4; ++c) {
                *(bf16x8*)&Bh[tid * PK + c * 8] = *(const bf16x8*)&sh[c * 8];
                *(bf16x8*)&Bl[tid * PK + c * 8] = *(const bf16x8*)&sl[c * 8];
            }
        }
        __syncthreads();

        // ---- MFMA: 16 frag-pairs x 3 products ----
        bf16x8 bh[4], bl[4];
#pragma unroll
        for (int nf = 0; nf < 4; ++nf) {
            int col = wcol + nf * 16 + l15;
            bh[nf] = *(const bf16x8*)&Bh[col * PK + kb];
            bl[nf] = *(const bf16x8*)&Bl[col * PK + kb];
        }
#pragma unroll
        for (int mf = 0; mf < 4; ++mf) {
            int r = mf * 16 + l15;
            bf16x8 ah = *(const bf16x8*)&Ah[r * PK + kb];
            bf16x8 al = *(const bf16x8*)&Al[r * PK + kb];
#pragma unroll
            for (int nf = 0; nf < 4; ++nf) {
                acc[mf][nf] = __builtin_amdgcn_mfma_f32_16x16x32_bf16(ah, bh[nf], acc[mf][nf], 0, 0, 0);
                acc[mf][nf] = __builtin_amdgcn_mfma_f32_16x16x32_bf16(ah, bl[nf], acc[mf][nf], 0, 0, 0);
                acc[mf][nf] = __builtin_amdgcn_mfma_f32_16x16x32_bf16(al, bh[nf], acc[mf][nf], 0, 0, 0);
            }
        }
    }

    // ---- store bf16: D row = 4*(lane>>4)+r, col = lane&15 ----
    const int orow = 4 * (lane >> 4);
#pragma unroll
    for (int mf = 0; mf < 4; ++mf) {
#pragma unroll
        for (int r = 0; r < 4; ++r) {
            int grow = row0 + mf * 16 + orow + r;
            if (grow < M) {
#pragma unroll
                for (int nf = 0; nf < 4; ++nf) {
                    C[(size_t)grow * 256 + wcol + nf * 16 + l15] = f2bf(acc[mf][nf][r]);
                }
            }
        }
    }
}

// ================= CSR aggregation: one wave per destination node =================
// agg[d,:] = xw[d,:]*dinv[d]^2 + sum_{e: dst=d} xw[src_e,:]*nrm_e
// xw is bf16 (halves the 402MB L2-miss gather traffic -- the measured bottleneck);
// accumulate fp32; unroll-4 kept (helps once traffic halves and latency re-emerges).

__global__ __launch_bounds__(256) void aggregate_kernel(const short* __restrict__ xw,
                                                        const int* __restrict__ row_ptr,
                                                        const int* __restrict__ counts,
                                                        const int* __restrict__ srcs,
                                                        const float* __restrict__ nrms,
                                                        const float* __restrict__ dinv,
                                                        float* __restrict__ agg) {
    int d = blockIdx.x * 4 + (threadIdx.x >> 6);
    if (d >= NN) return;
    int lane = threadIdx.x & 63;
    const size_t coff = (size_t)(lane * 4);

    float di = dinv[d];
    float s2 = di * di;
    bf16x4 sv = *(const bf16x4*)&xw[(size_t)d * 256 + coff];
    float4 acc;
    acc.x = bf2f(sv[0]) * s2;
    acc.y = bf2f(sv[1]) * s2;
    acc.z = bf2f(sv[2]) * s2;
    acc.w = bf2f(sv[3]) * s2;

    int j = row_ptr[d];
    int cnt = counts[d];

    for (; cnt >= 4; cnt -= 4, j += 4) {
        int s0 = srcs[j + 0], s1 = srcs[j + 1], s2i = srcs[j + 2], s3 = srcs[j + 3];
        float w0 = nrms[j + 0], w1 = nrms[j + 1], w2 = nrms[j + 2], w3 = nrms[j + 3];
        bf16x4 v0 = *(const bf16x4*)&xw[(size_t)s0 * 256 + coff];
        bf16x4 v1 = *(const bf16x4*)&xw[(size_t)s1 * 256 + coff];
        bf16x4 v2 = *(const bf16x4*)&xw[(size_t)s2i * 256 + coff];
        bf16x4 v3 = *(const bf16x4*)&xw[(size_t)s3 * 256 + coff];
        acc.x = fmaf(bf2f(v0[0]), w0, acc.x); acc.y = fmaf(bf2f(v0[1]), w0, acc.y);
        acc.z = fmaf(bf2f(v0[2]), w0, acc.z); acc.w = fmaf(bf2f(v0[3]), w0, acc.w);
        acc.x = fmaf(bf2f(v1[0]), w1, acc.x); acc.y = fmaf(bf2f(v1[1]), w1, acc.y);
        acc.z = fmaf(bf2f(v1[2]), w1, acc.z); acc.w = fmaf(bf2f(v1[3]), w1, acc.w);
        acc.x = fmaf(bf2f(v2[0]), w2, acc.x); acc.y = fmaf(bf2f(v2[1]), w2, acc.y);
        acc.z = fmaf(bf2f(v2[2]), w2, acc.z); acc.w = fmaf(bf2f(v2[3]), w2, acc.w);
        acc.x = fmaf(bf2f(v3[0]), w3, acc.x); acc.y = fmaf(bf2f(v3[1]), w3, acc.y);
        acc.z = fmaf(bf2f(v3[2]), w3, acc.z); acc.w = fmaf(bf2f(v3[3]), w3, acc.w);
    }
    for (; cnt > 0; --cnt, ++j) {
        int s_ = srcs[j];
        float w = nrms[j];
        bf16x4 v = *(const bf16x4*)&xw[(size_t)s_ * 256 + coff];
        acc.x = fmaf(bf2f(v[0]), w, acc.x);
        acc.y = fmaf(bf2f(v[1]), w, acc.y);
        acc.z = fmaf(bf2f(v[2]), w, acc.z);
        acc.w = fmaf(bf2f(v[3]), w, acc.w);
    }
    *(float4*)&agg[(size_t)d * 256 + coff] = acc;
}

// ================= fused epilogue: wave per node =================
// out[i] = (agg2[i,:]+b2) . Wf[0:256] + relu(tf[i,:]@Wt+bt) . Wf[256:512] + bf

__global__ __launch_bounds__(256) void final_kernel(const float* __restrict__ agg2,
                                                    const float* __restrict__ b2,
                                                    const float* __restrict__ tf,
                                                    const float* __restrict__ Wt,
                                                    const float* __restrict__ bt,
                                                    const float* __restrict__ Wf,
                                                    const float* __restrict__ bf,
                                                    float* __restrict__ out) {
    int d = blockIdx.x * 4 + (threadIdx.x >> 6);
    if (d >= NN) return;
    int lane = threadIdx.x & 63;
    int c0 = lane * 4;

    float4 g   = *(const float4*)&agg2[(size_t)d * 256 + c0];
    float4 b2v = *(const float4*)&b2[c0];
    float4 wf0 = *(const float4*)&Wf[c0];
    float4 wf1 = *(const float4*)&Wf[256 + c0];
    float4 wt0 = *(const float4*)&Wt[c0];        // Wt row 0
    float4 wt1 = *(const float4*)&Wt[256 + c0];  // Wt row 1
    float4 btv = *(const float4*)&bt[c0];
    float t0 = tf[d * 2 + 0], t1 = tf[d * 2 + 1];

    float acc = (g.x + b2v.x) * wf0.x + (g.y + b2v.y) * wf0.y +
                (g.z + b2v.z) * wf0.z + (g.w + b2v.w) * wf0.w;
    float xt;
    xt = fmaxf(fmaf(t0, wt0.x, fmaf(t1, wt1.x, btv.x)), 0.f); acc = fmaf(xt, wf1.x, acc);
    xt = fmaxf(fmaf(t0, wt0.y, fmaf(t1, wt1.y, btv.y)), 0.f); acc = fmaf(xt, wf1.y, acc);
    xt = fmaxf(fmaf(t0, wt0.z, fmaf(t1, wt1.z, btv.z)), 0.f); acc = fmaf(xt, wf1.z, acc);
    xt = fmaxf(fmaf(t0, wt0.w, fmaf(t1, wt1.w, btv.w)), 0.f); acc = fmaf(xt, wf1.w, acc);

    acc += __shfl_down(acc, 32);
    acc += __shfl_down(acc, 16);
    acc += __shfl_down(acc, 8);
    acc += __shfl_down(acc, 4);
    acc += __shfl_down(acc, 2);
    acc += __shfl_down(acc, 1);
    if (lane == 0) out[d] = acc + bf[0];
}

// ================= launch =================

extern "C" void kernel_launch(void* const* d_in, const int* in_sizes, int n_in,
                              void* d_out, int out_size, void* d_ws, size_t ws_size,
                              hipStream_t stream) {
    const float* x  = (const float*)d_in[0];
    const int*   ei = (const int*)d_in[1];      // [2, NE] int32
    const float* tf = (const float*)d_in[2];
    const float* W1 = (const float*)d_in[3];
    const float* b1 = (const float*)d_in[4];
    const float* W2 = (const float*)d_in[5];
    const float* b2 = (const float*)d_in[6];
    const float* Wt = (const float*)d_in[7];
    const float* bt = (const float*)d_in[8];
    const float* Wf = (const float*)d_in[9];
    const float* bf = (const float*)d_in[10];
    const int* srcp = ei;
    const int* dstp = ei + NE;

    // workspace layout -- byte-identical to the round-2 layout that passed on-device
    char* ws = (char*)d_ws;
    short* Axw     = (short*)(ws);                       // bf16 xw (25.6MB used of 51.2 slot)
    float* B       = (float*)(ws + 51200000);            // fp32 agg1/agg2
    char*  p       = ws + 102400000;
    int*   counts  = (int*)(p);            p += 204800;
    float* dinv    = (float*)(p);          p += 204800;
    int*   row_ptr = (int*)(p);            p += 204800;
    int*   cursor  = (int*)(p);            p += 204800;
    int*   partials= (int*)(p);            p += 4096;
    int*   chunkoff= (int*)(p);            p += 4096;
    int*   srcs    = (int*)(p);            p += 3200000;
    float* nrms    = (float*)(p);          p += 3200000;
    short* Wh1     = (short*)(p);          p += 131072;
    short* Wl1     = (short*)(p);          p += 131072;
    short* Wh2     = (short*)(p);          p += 131072;
    short* Wl2     = (short*)(p);          p += 131072;
    // total ~110.3 MB (== round-2 proven footprint)

    // ---- CSR build (d_ws poisoned 0xAA every call -> zero counts first) ----
    hipMemsetAsync(counts, 0, NN * sizeof(int), stream);
    deg_count_kernel<<<(NE + 255) / 256, 256, 0, stream>>>(dstp, counts);
    chunk_sum_kernel<<<NCHUNK, 256, 0, stream>>>(counts, partials);
    scan_partials_kernel<<<1, 256, 0, stream>>>(partials, chunkoff);
    scan_chunks_kernel<<<NCHUNK, 256, 0, stream>>>(counts, chunkoff, row_ptr, cursor, dinv);
    fill_csr_kernel<<<(NE + 255) / 256, 256, 0, stream>>>(srcp, dstp, dinv, cursor, srcs, nrms);

    // ---- weight split (independent of CSR chain) ----
    wconv_kernel<<<256, 256, 0, stream>>>(W1, Wh1, Wl1);
    wconv_kernel<<<256, 256, 0, stream>>>(W2, Wh2, Wl2);

    int gemm_grid = (NN + BM - 1) / BM;  // 782
    dim3 agg_grid((NN + 3) / 4);

    // layer 1
    mgemm_kernel<false><<<gemm_grid, 256, 0, stream>>>(x, Wh1, Wl1, nullptr, Axw, NN);
    aggregate_kernel<<<agg_grid, 256, 0, stream>>>(Axw, row_ptr, counts, srcs, nrms, dinv, B);

    // layer 2 (bias1+relu fused into GEMM A-load)
    mgemm_kernel<true><<<gemm_grid, 256, 0, stream>>>(B, Wh2, Wl2, b1, Axw, NN);
    aggregate_kernel<<<agg_grid, 256, 0, stream>>>(Axw, row_ptr, counts, srcs, nrms, dinv, B);

    // epilogue
    final_kernel<<<agg_grid, 256, 0, stream>>>(B, b2, tf, Wt, bt, Wf, bf, (float*)d_out);
}

// Round 14
// 425.782 us; speedup vs baseline: 1.5173x; 1.0184x over previous
//
#include <hip/hip_runtime.h>

#define NN 50000
#define NE 800000
#define NCHUNK 196  // ceil(NN/256)

typedef __attribute__((ext_vector_type(4))) float f32x4;
typedef __attribute__((ext_vector_type(8))) short bf16x8;
typedef __attribute__((ext_vector_type(4))) short bf16x4;

// bf16 round-to-nearest-even helpers
__device__ __forceinline__ short f2bf(float x) {
    unsigned u = __float_as_uint(x);
    unsigned r = (u + 0x7fffu + ((u >> 16) & 1u)) >> 16;
    return (short)r;
}
__device__ __forceinline__ float bf2f(short s) {
    return __uint_as_float(((unsigned)(unsigned short)s) << 16);
}

// ================= CSR build =================

__global__ void deg_count_kernel(const int* __restrict__ dst, int* __restrict__ counts) {
    int e = blockIdx.x * 256 + threadIdx.x;
    if (e < NE) atomicAdd(&counts[dst[e]], 1);
}

__global__ void chunk_sum_kernel(const int* __restrict__ counts, int* __restrict__ partials) {
    int i = blockIdx.x * 256 + threadIdx.x;
    int v = (i < NN) ? counts[i] : 0;
    for (int o = 32; o; o >>= 1) v += __shfl_down(v, o);
    __shared__ int red[4];
    if ((threadIdx.x & 63) == 0) red[threadIdx.x >> 6] = v;
    __syncthreads();
    if (threadIdx.x == 0) partials[blockIdx.x] = red[0] + red[1] + red[2] + red[3];
}

__global__ void scan_partials_kernel(const int* __restrict__ partials, int* __restrict__ chunk_off) {
    __shared__ int s[256];
    int t = threadIdx.x;
    int v = (t < NCHUNK) ? partials[t] : 0;
    s[t] = v;
    __syncthreads();
    for (int o = 1; o < 256; o <<= 1) {
        int u = (t >= o) ? s[t - o] : 0;
        __syncthreads();
        s[t] += u;
        __syncthreads();
    }
    chunk_off[t] = s[t] - v;  // exclusive
}

__global__ void scan_chunks_kernel(const int* __restrict__ counts, const int* __restrict__ chunk_off,
                                   int* __restrict__ row_ptr, int* __restrict__ cursor,
                                   float* __restrict__ dinv) {
    __shared__ int s[256];
    int b = blockIdx.x, t = threadIdx.x;
    int i = b * 256 + t;
    int c = (i < NN) ? counts[i] : 0;
    s[t] = c;
    __syncthreads();
    for (int o = 1; o < 256; o <<= 1) {
        int u = (t >= o) ? s[t - o] : 0;
        __syncthreads();
        s[t] += u;
        __syncthreads();
    }
    if (i < NN) {
        int start = chunk_off[b] + s[t] - c;  // exclusive prefix
        row_ptr[i] = start;
        cursor[i]  = start;
        dinv[i] = rsqrtf((float)(c + 1));  // +1 self loop
    }
}

// packed edge: {src, norm_bits} -- one 8B random store here, one 8B stream read in aggregate
__global__ void fill_csr_kernel(const int* __restrict__ src, const int* __restrict__ dst,
                                const float* __restrict__ dinv, int* __restrict__ cursor,
                                int2* __restrict__ edges) {
    int e = blockIdx.x * 256 + threadIdx.x;
    if (e >= NE) return;
    int s_ = src[e], d = dst[e];
    int p = atomicAdd(&cursor[d], 1);
    edges[p] = make_int2(s_, __float_as_int(dinv[s_] * dinv[d]));
}

// ================= W pre-pass: transpose + split to bf16 hi/lo =================
// in:  W [K=256][N=256] row-major fp32 ; out: Wh/Wl [N][K] bf16 bits

__global__ void wconv_kernel(const float* __restrict__ W, short* __restrict__ Wh,
                             short* __restrict__ Wl) {
    int idx = blockIdx.x * 256 + threadIdx.x;  // 65536
    int k = idx >> 8, n = idx & 255;
    float x = W[idx];
    short h = f2bf(x);
    short l = f2bf(x - bf2f(h));
    Wh[n * 256 + k] = h;
    Wl[n * 256 + k] = l;
}

// ================= split-bf16 MFMA GEMM: C_bf16[M,256] = act(A[M,256]) @ W =================
// A fp32 -> hi/lo bf16 split during LDS staging; W pre-split/pre-transposed.
// C stored bf16 (halves the gather-bound aggregate's traffic -- measured lever).
// hi*hi + hi*lo + lo*hi (lo*lo dropped) -> ~fp32 mantissa.
// act = relu(a + bias[k]) when RELU_BIAS (fuses layer-1 bias+relu into GEMM2's A-load).

#define BM 64
#define BK 32
#define PK 40  // padded k-stride in LDS (80B rows -> 2-way banks, free)

template <bool RELU_BIAS>
__global__ __launch_bounds__(256) void mgemm_kernel(const float* __restrict__ A,
                                                    const short* __restrict__ Wh,
                                                    const short* __restrict__ Wl,
                                                    const float* __restrict__ bias,
                                                    short* __restrict__ C, int M) {
    __shared__ __align__(16) short Ah[BM * PK], Al[BM * PK];
    __shared__ __align__(16) short Bh[256 * PK], Bl[256 * PK];
    const int tid  = threadIdx.x;
    const int lane = tid & 63;
    const int wave = tid >> 6;
    const int row0 = blockIdx.x * BM;
    const int wcol = wave * 64;   // this wave's 64-col slice of N=256

    const int l15 = lane & 15;
    const int kb  = (lane >> 4) * 8;   // k-block of this lane within frag

    const int arow  = tid >> 2;        // 0..63   A staging row
    const int akoff = (tid & 3) * 8;   // 0,8,16,24

    f32x4 acc[4][4] = {};  // [mf][nf] 16x16 frags -> 64x64 per wave

    for (int k0 = 0; k0 < 256; k0 += BK) {
        // ---- load + convert A slice ----
        float xv[8];
        int grow = row0 + arow;
        if (grow < M) {
            float4 a0 = *(const float4*)&A[(size_t)grow * 256 + k0 + akoff];
            float4 a1 = *(const float4*)&A[(size_t)grow * 256 + k0 + akoff + 4];
            xv[0] = a0.x; xv[1] = a0.y; xv[2] = a0.z; xv[3] = a0.w;
            xv[4] = a1.x; xv[5] = a1.y; xv[6] = a1.z; xv[7] = a1.w;
        } else {
#pragma unroll
            for (int i = 0; i < 8; ++i) xv[i] = 0.f;
        }
        if (RELU_BIAS) {
#pragma unroll
            for (int i = 0; i < 8; ++i) xv[i] = fmaxf(xv[i] + bias[k0 + akoff + i], 0.f);
        }
        bf16x8 hv, lv;
#pragma unroll
        for (int i = 0; i < 8; ++i) {
            short h = f2bf(xv[i]);
            hv[i] = h;
            lv[i] = f2bf(xv[i] - bf2f(h));
        }

        __syncthreads();  // previous iter's frag reads done before overwrite
        *(bf16x8*)&Ah[arow * PK + akoff] = hv;
        *(bf16x8*)&Al[arow * PK + akoff] = lv;

        // ---- stage B slice: thread t owns row n=t (vector loads, pre-split W) ----
        {
            const short* sh = &Wh[tid * 256 + k0];
            const short* sl = &Wl[tid * 256 + k0];
#pragma unroll
            for (int c = 0; c < 4; ++c) {
                *(bf16x8*)&Bh[tid * PK + c * 8] = *(const bf16x8*)&sh[c * 8];
                *(bf16x8*)&Bl[tid * PK + c * 8] = *(const bf16x8*)&sl[c * 8];
            }
        }
        __syncthreads();

        // ---- MFMA: 16 frag-pairs x 3 products ----
        bf16x8 bh[4], bl[4];
#pragma unroll
        for (int nf = 0; nf < 4; ++nf) {
            int col = wcol + nf * 16 + l15;
            bh[nf] = *(const bf16x8*)&Bh[col * PK + kb];
            bl[nf] = *(const bf16x8*)&Bl[col * PK + kb];
        }
#pragma unroll
        for (int mf = 0; mf < 4; ++mf) {
            int r = mf * 16 + l15;
            bf16x8 ah = *(const bf16x8*)&Ah[r * PK + kb];
            bf16x8 al = *(const bf16x8*)&Al[r * PK + kb];
#pragma unroll
            for (int nf = 0; nf < 4; ++nf) {
                acc[mf][nf] = __builtin_amdgcn_mfma_f32_16x16x32_bf16(ah, bh[nf], acc[mf][nf], 0, 0, 0);
                acc[mf][nf] = __builtin_amdgcn_mfma_f32_16x16x32_bf16(ah, bl[nf], acc[mf][nf], 0, 0, 0);
                acc[mf][nf] = __builtin_amdgcn_mfma_f32_16x16x32_bf16(al, bh[nf], acc[mf][nf], 0, 0, 0);
            }
        }
    }

    // ---- store bf16: D row = 4*(lane>>4)+r, col = lane&15 ----
    const int orow = 4 * (lane >> 4);
#pragma unroll
    for (int mf = 0; mf < 4; ++mf) {
#pragma unroll
        for (int r = 0; r < 4; ++r) {
            int grow = row0 + mf * 16 + orow + r;
            if (grow < M) {
#pragma unroll
                for (int nf = 0; nf < 4; ++nf) {
                    C[(size_t)grow * 256 + wcol + nf * 16 + l15] = f2bf(acc[mf][nf][r]);
                }
            }
        }
    }
}

// ================= CSR aggregation: TWO nodes per wave (half-wave each) =================
// agg[d,:] = xw[d,:]*dinv[d]^2 + sum_{e: dst=d} xw[src_e,:]*nrm_e
// Half-wave = 32 lanes x bf16x8 (16B/lane) covers one 256-ch row -> doubles bytes
// in flight per vmem slot vs the 8B/lane version (measured: 49% HBM, 27% VALU =>
// latency-limited, not traffic- or issue-limited). Same per-channel accumulation
// order as before => bitwise-identical numerics.

__global__ __launch_bounds__(256) void aggregate_kernel(const short* __restrict__ xw,
                                                        const int* __restrict__ row_ptr,
                                                        const int* __restrict__ counts,
                                                        const int2* __restrict__ edges,
                                                        const float* __restrict__ dinv,
                                                        float* __restrict__ agg) {
    int d = blockIdx.x * 8 + (threadIdx.x >> 5);  // 8 half-waves per block
    if (d >= NN) return;
    int lane = threadIdx.x & 31;
    const size_t coff = (size_t)(lane * 8);       // this lane's 8-channel slice

    float di = dinv[d];
    float s2 = di * di;
    bf16x8 sv = *(const bf16x8*)&xw[(size_t)d * 256 + coff];
    float acc[8];
#pragma unroll
    for (int i = 0; i < 8; ++i) acc[i] = bf2f(sv[i]) * s2;

    int j = row_ptr[d];
    int end = j + counts[d];

    for (; j + 4 <= end; j += 4) {
        int2 e0 = edges[j + 0], e1 = edges[j + 1], e2 = edges[j + 2], e3 = edges[j + 3];
        bf16x8 v0 = *(const bf16x8*)&xw[(size_t)e0.x * 256 + coff];
        bf16x8 v1 = *(const bf16x8*)&xw[(size_t)e1.x * 256 + coff];
        bf16x8 v2 = *(const bf16x8*)&xw[(size_t)e2.x * 256 + coff];
        bf16x8 v3 = *(const bf16x8*)&xw[(size_t)e3.x * 256 + coff];
        float w0 = __int_as_float(e0.y), w1 = __int_as_float(e1.y);
        float w2 = __int_as_float(e2.y), w3 = __int_as_float(e3.y);
#pragma unroll
        for (int i = 0; i < 8; ++i) acc[i] = fmaf(bf2f(v0[i]), w0, acc[i]);
#pragma unroll
        for (int i = 0; i < 8; ++i) acc[i] = fmaf(bf2f(v1[i]), w1, acc[i]);
#pragma unroll
        for (int i = 0; i < 8; ++i) acc[i] = fmaf(bf2f(v2[i]), w2, acc[i]);
#pragma unroll
        for (int i = 0; i < 8; ++i) acc[i] = fmaf(bf2f(v3[i]), w3, acc[i]);
    }
    for (; j < end; ++j) {
        int2 e = edges[j];
        float w = __int_as_float(e.y);
        bf16x8 v = *(const bf16x8*)&xw[(size_t)e.x * 256 + coff];
#pragma unroll
        for (int i = 0; i < 8; ++i) acc[i] = fmaf(bf2f(v[i]), w, acc[i]);
    }

    float* o = &agg[(size_t)d * 256 + coff];
    *(float4*)&o[0] = make_float4(acc[0], acc[1], acc[2], acc[3]);
    *(float4*)&o[4] = make_float4(acc[4], acc[5], acc[6], acc[7]);
}

// ================= fused epilogue: wave per node =================
// out[i] = (agg2[i,:]+b2) . Wf[0:256] + relu(tf[i,:]@Wt+bt) . Wf[256:512] + bf

__global__ __launch_bounds__(256) void final_kernel(const float* __restrict__ agg2,
                                                    const float* __restrict__ b2,
                                                    const float* __restrict__ tf,
                                                    const float* __restrict__ Wt,
                                                    const float* __restrict__ bt,
                                                    const float* __restrict__ Wf,
                                                    const float* __restrict__ bf,
                                                    float* __restrict__ out) {
    int d = blockIdx.x * 4 + (threadIdx.x >> 6);
    if (d >= NN) return;
    int lane = threadIdx.x & 63;
    int c0 = lane * 4;

    float4 g   = *(const float4*)&agg2[(size_t)d * 256 + c0];
    float4 b2v = *(const float4*)&b2[c0];
    float4 wf0 = *(const float4*)&Wf[c0];
    float4 wf1 = *(const float4*)&Wf[256 + c0];
    float4 wt0 = *(const float4*)&Wt[c0];        // Wt row 0
    float4 wt1 = *(const float4*)&Wt[256 + c0];  // Wt row 1
    float4 btv = *(const float4*)&bt[c0];
    float t0 = tf[d * 2 + 0], t1 = tf[d * 2 + 1];

    float acc = (g.x + b2v.x) * wf0.x + (g.y + b2v.y) * wf0.y +
                (g.z + b2v.z) * wf0.z + (g.w + b2v.w) * wf0.w;
    float xt;
    xt = fmaxf(fmaf(t0, wt0.x, fmaf(t1, wt1.x, btv.x)), 0.f); acc = fmaf(xt, wf1.x, acc);
    xt = fmaxf(fmaf(t0, wt0.y, fmaf(t1, wt1.y, btv.y)), 0.f); acc = fmaf(xt, wf1.y, acc);
    xt = fmaxf(fmaf(t0, wt0.z, fmaf(t1, wt1.z, btv.z)), 0.f); acc = fmaf(xt, wf1.z, acc);
    xt = fmaxf(fmaf(t0, wt0.w, fmaf(t1, wt1.w, btv.w)), 0.f); acc = fmaf(xt, wf1.w, acc);

    acc += __shfl_down(acc, 32);
    acc += __shfl_down(acc, 16);
    acc += __shfl_down(acc, 8);
    acc += __shfl_down(acc, 4);
    acc += __shfl_down(acc, 2);
    acc += __shfl_down(acc, 1);
    if (lane == 0) out[d] = acc + bf[0];
}

// ================= launch =================

extern "C" void kernel_launch(void* const* d_in, const int* in_sizes, int n_in,
                              void* d_out, int out_size, void* d_ws, size_t ws_size,
                              hipStream_t stream) {
    const float* x  = (const float*)d_in[0];
    const int*   ei = (const int*)d_in[1];      // [2, NE] int32
    const float* tf = (const float*)d_in[2];
    const float* W1 = (const float*)d_in[3];
    const float* b1 = (const float*)d_in[4];
    const float* W2 = (const float*)d_in[5];
    const float* b2 = (const float*)d_in[6];
    const float* Wt = (const float*)d_in[7];
    const float* bt = (const float*)d_in[8];
    const float* Wf = (const float*)d_in[9];
    const float* bf = (const float*)d_in[10];
    const int* srcp = ei;
    const int* dstp = ei + NE;

    // workspace layout -- same 110.3 MB proven footprint (srcs+nrms fused into edges)
    char* ws = (char*)d_ws;
    short* Axw     = (short*)(ws);                       // bf16 xw (25.6MB of 51.2 slot)
    float* B       = (float*)(ws + 51200000);            // fp32 agg1/agg2
    char*  p       = ws + 102400000;
    int*   counts  = (int*)(p);            p += 204800;
    float* dinv    = (float*)(p);          p += 204800;
    int*   row_ptr = (int*)(p);            p += 204800;
    int*   cursor  = (int*)(p);            p += 204800;
    int*   partials= (int*)(p);            p += 4096;
    int*   chunkoff= (int*)(p);            p += 4096;
    int2*  edges   = (int2*)(p);           p += 6400000; // packed {src, nrm}
    short* Wh1     = (short*)(p);          p += 131072;
    short* Wl1     = (short*)(p);          p += 131072;
    short* Wh2     = (short*)(p);          p += 131072;
    short* Wl2     = (short*)(p);          p += 131072;

    // ---- CSR build (d_ws poisoned 0xAA every call -> zero counts first) ----
    hipMemsetAsync(counts, 0, NN * sizeof(int), stream);
    deg_count_kernel<<<(NE + 255) / 256, 256, 0, stream>>>(dstp, counts);
    chunk_sum_kernel<<<NCHUNK, 256, 0, stream>>>(counts, partials);
    scan_partials_kernel<<<1, 256, 0, stream>>>(partials, chunkoff);
    scan_chunks_kernel<<<NCHUNK, 256, 0, stream>>>(counts, chunkoff, row_ptr, cursor, dinv);
    fill_csr_kernel<<<(NE + 255) / 256, 256, 0, stream>>>(srcp, dstp, dinv, cursor, edges);

    // ---- weight split (independent of CSR chain) ----
    wconv_kernel<<<256, 256, 0, stream>>>(W1, Wh1, Wl1);
    wconv_kernel<<<256, 256, 0, stream>>>(W2, Wh2, Wl2);

    int gemm_grid = (NN + BM - 1) / BM;  // 782
    int agg_grid = (NN + 7) / 8;         // 6250 (8 half-waves per block)
    int fin_grid = (NN + 3) / 4;

    // layer 1
    mgemm_kernel<false><<<gemm_grid, 256, 0, stream>>>(x, Wh1, Wl1, nullptr, Axw, NN);
    aggregate_kernel<<<agg_grid, 256, 0, stream>>>(Axw, row_ptr, counts, edges, dinv, B);

    // layer 2 (bias1+relu fused into GEMM A-load)
    mgemm_kernel<true><<<gemm_grid, 256, 0, stream>>>(B, Wh2, Wl2, b1, Axw, NN);
    aggregate_kernel<<<agg_grid, 256, 0, stream>>>(Axw, row_ptr, counts, edges, dinv, B);

    // epilogue
    final_kernel<<<fin_grid, 256, 0, stream>>>(B, b2, tf, Wt, bt, Wf, bf, (float*)d_out);
}